// Round 13
// baseline (795.145 us; speedup 1.0000x reference)
//
#include <hip/hip_runtime.h>
#include <hip/hip_cooperative_groups.h>

#define DIM 128
namespace cg = cooperative_groups;

typedef __attribute__((ext_vector_type(8))) short bf16x8;
typedef __attribute__((ext_vector_type(4))) float f32x4;

// ---- bf16 helpers (RNE) ----------------------------------------------------
__device__ inline unsigned short to_bf16(float f) {
    unsigned u = __float_as_uint(f);
    u = (u + 0x7FFFu + ((u >> 16) & 1u)) >> 16;
    return (unsigned short)u;
}
__device__ inline unsigned pack_bf16(float lo, float hi) {
    return (unsigned)to_bf16(lo) | ((unsigned)to_bf16(hi) << 16);
}
__device__ inline float unpack_lo(unsigned v) { return __uint_as_float(v << 16); }
__device__ inline float unpack_hi(unsigned v) { return __uint_as_float(v & 0xFFFF0000u); }

// ---------------------------------------------------------------------------
__global__ void wprep_kernel(const float* __restrict__ W_a, unsigned short* __restrict__ Wt,
                             int* __restrict__ counts, int n) {
    const int c = blockIdx.x;          // 0..255
    const int k = threadIdx.x;         // 0..127
    const int srow = (c < 128) ? k : (256 + k);
    const int scol = (c < 128) ? c : (c - 128);
    Wt[c * DIM + k] = to_bf16(W_a[srow * DIM + scol]);
    for (int i = blockIdx.x * 128 + k; i < n; i += 256 * 128) counts[i] = 0;
}

// ---------------------------------------------------------------------------
// Fused stage 1 (512 threads/block): GEMM (both halves) | hist | rel-proj
// ---------------------------------------------------------------------------
__global__ __launch_bounds__(512, 4) void stage1_kernel(
        const float* __restrict__ ent, const float* __restrict__ rel,
        const int* __restrict__ T, const unsigned short* __restrict__ Wt,
        const float* __restrict__ W_rel, const float* __restrict__ b_a,
        const float* __restrict__ Wa2,
        unsigned* __restrict__ P1h, unsigned* __restrict__ P3h, unsigned* __restrict__ P2h,
        float* __restrict__ q1, float* __restrict__ q3, float* __restrict__ q2,
        int* __restrict__ counts, int NE, int NR, int E, int GB, int HB, int RB) {
    __shared__ unsigned smem[16640];   // 66.6 KB: B [256][64]dw swz / out [256][65]dw
    int b = blockIdx.x;
    const int t = threadIdx.x;

    if (b < GB) {
        const int mrow = b * 128;
        const int wv = t >> 6;
        const int lane = t & 63;
        const int g = lane >> 4, m = lane & 15;

        #pragma unroll
        for (int i = 0; i < 8; ++i) {
            const int ci  = i * 8 + wv;
            const int row = ci * 4 + (lane >> 4);
            const int dw0 = (lane & 15) * 4;
            const int sdw = dw0 ^ ((row & 7) << 2);
            const uint4 v = *(const uint4*)(Wt + row * DIM + sdw * 2);
            *(uint4*)&smem[ci * 256 + lane * 4] = v;
        }

        const int rowA = min(mrow + wv * 16 + m, NE - 1);
        const float* arow = ent + (size_t)rowA * DIM;
        bf16x8 afrag[4];
        #pragma unroll
        for (int kk = 0; kk < 4; ++kk) {
            const float4 u0 = *(const float4*)(arow + kk * 32 + g * 8);
            const float4 u1 = *(const float4*)(arow + kk * 32 + g * 8 + 4);
            bf16x8 a;
            a[0] = (short)to_bf16(u0.x); a[1] = (short)to_bf16(u0.y);
            a[2] = (short)to_bf16(u0.z); a[3] = (short)to_bf16(u0.w);
            a[4] = (short)to_bf16(u1.x); a[5] = (short)to_bf16(u1.y);
            a[6] = (short)to_bf16(u1.z); a[7] = (short)to_bf16(u1.w);
            afrag[kk] = a;
        }
        __syncthreads();

        f32x4 acc[2][8];
        #pragma unroll
        for (int h = 0; h < 2; ++h)
            #pragma unroll
            for (int ct = 0; ct < 8; ++ct) acc[h][ct] = (f32x4){0.f, 0.f, 0.f, 0.f};
        #pragma unroll
        for (int kk = 0; kk < 4; ++kk) {
            #pragma unroll
            for (int h = 0; h < 2; ++h) {
                #pragma unroll
                for (int ct = 0; ct < 8; ++ct) {
                    const int brow = h * 128 + ct * 16 + m;
                    const int dw = (kk * 16 + g * 4) ^ ((brow & 7) << 2);
                    const bf16x8 bb = *(const bf16x8*)&smem[brow * 64 + dw];
                    acc[h][ct] = __builtin_amdgcn_mfma_f32_16x16x32_bf16(afrag[kk], bb, acc[h][ct], 0, 0, 0);
                }
            }
        }
        __syncthreads();

        unsigned short* lds16 = (unsigned short*)smem;   // [256][130] ushort
        #pragma unroll
        for (int h = 0; h < 2; ++h) {
            float* __restrict__ qo = h ? q3 : q1;
            float qp[4] = {0.f, 0.f, 0.f, 0.f};
            #pragma unroll
            for (int ct = 0; ct < 8; ++ct) {
                const int c = ct * 16 + m;
                const float bias = h ? 0.0f : b_a[c];
                const float wa2  = Wa2[c];
                #pragma unroll
                for (int r = 0; r < 4; ++r) {
                    const float v = acc[h][ct][r] + bias;
                    qp[r] += v * wa2;
                    lds16[(h * 128 + wv * 16 + g * 4 + r) * 130 + c] = to_bf16(v);
                }
            }
            #pragma unroll
            for (int r = 0; r < 4; ++r) {
                float v = qp[r];
                #pragma unroll
                for (int o = 1; o < 16; o <<= 1) v += __shfl_xor(v, o);
                const int row = mrow + wv * 16 + g * 4 + r;
                if (m == 0 && row < NE) qo[row] = v;
            }
        }
        __syncthreads();
        #pragma unroll 4
        for (int i = 0; i < 32; ++i) {
            const int linear = i * 512 + t;
            const int row = linear >> 6, d = linear & 63;
            const int rg = mrow + (row & 127);
            unsigned* __restrict__ Ph = (row < 128) ? P1h : P3h;
            if (rg < NE) Ph[(size_t)rg * 64 + d] = smem[row * 65 + d];
        }
        return;
    }
    b -= GB;

    if (b < HB) {
        for (int e = b * 512 + t; e < E; e += HB * 512)
            atomicAdd(&counts[T[e]], 1);
        return;
    }
    b -= HB;

    {
        float* xs   = (float*)smem;
        float* sred = (float*)(smem + 2048);
        const int row0 = b * 16;
        const int qr = t >> 7;
        const int tc = t & 127;
        #pragma unroll
        for (int e = 0; e < 4; ++e) {
            int row = row0 + qr * 4 + e;
            xs[(qr * 4 + e) * DIM + tc] = (row < NR) ? rel[(size_t)row * DIM + tc] : 0.0f;
        }
        __syncthreads();
        float acc[4] = {0.f, 0.f, 0.f, 0.f};
        #pragma unroll 4
        for (int k = 0; k < DIM; ++k) {
            const float wv = W_rel[k * DIM + tc];
            #pragma unroll
            for (int e = 0; e < 4; ++e) acc[e] += xs[(qr * 4 + e) * DIM + k] * wv;
        }
        const float wa2 = Wa2[tc];
        const int lane = t & 63;
        #pragma unroll
        for (int e = 0; e < 4; ++e) {
            float v = acc[e] * wa2;
            #pragma unroll
            for (int o = 32; o > 0; o >>= 1) v += __shfl_down(v, o);
            if (lane == 0) sred[(qr * 4 + e) * 2 + ((t >> 6) & 1)] = v;
        }
        __syncthreads();
        #pragma unroll
        for (int e = 0; e < 4; ++e) {
            int row = row0 + qr * 4 + e;
            float hi = __shfl_down(acc[e], 1);
            if (row < NR && (tc & 1) == 0)
                P2h[(size_t)row * 64 + (tc >> 1)] = pack_bf16(acc[e], hi);
        }
        if (t < 16) {
            int row = row0 + t;
            if (row < NR) q2[row] = sred[t * 2] + sred[t * 2 + 1];
        }
    }
}

// ---------------------------------------------------------------------------
__device__ inline int wave_incl_scan(int v) {
    const int lane = threadIdx.x & 63;
    #pragma unroll
    for (int o = 1; o < 64; o <<= 1) {
        int u = __shfl_up(v, o);
        if (lane >= o) v += u;
    }
    return v;
}

// ---- shared device helpers for phases (used by coop kernel AND fallbacks) --
__device__ inline void phaseA_bsum(const int* counts, int* bsum, int NE, int b, int t, int* ws) {
    const int base = b * 1024 + t * 4;
    int s = 0;
    #pragma unroll
    for (int j = 0; j < 4; ++j) if (base + j < NE) s += counts[base + j];
    #pragma unroll
    for (int o = 32; o > 0; o >>= 1) s += __shfl_down(s, o);
    if ((t & 63) == 0) ws[t >> 6] = s;
    __syncthreads();
    if (t == 0) bsum[b] = ws[0] + ws[1] + ws[2] + ws[3];
}

__device__ inline void phaseB_write(const int* counts, const int* bsum, int* offsets,
                                    int* cursor, int NE, int E, int NB, int b, int t,
                                    int* s_boff, int* wsum, int* wpre) {
    if (t < 64) {
        int v = (t < NB) ? bsum[t] : 0;
        int incl = wave_incl_scan(v);
        int ex = incl - v;
        int want = __shfl(ex, b);
        if (t == 0) *s_boff = want;
    }
    const int base = b * 1024 + t * 4;
    int c[4];
    int s = 0;
    #pragma unroll
    for (int j = 0; j < 4; ++j) {
        c[j] = (base + j < NE) ? counts[base + j] : 0;
        s += c[j];
    }
    int incl = wave_incl_scan(s);
    const int wid = t >> 6, lane = t & 63;
    if (lane == 63) wsum[wid] = incl;
    __syncthreads();
    if (t == 0) {
        int run = 0;
        #pragma unroll
        for (int k = 0; k < 4; ++k) { wpre[k] = run; run += wsum[k]; }
    }
    __syncthreads();
    int run = incl - s + wpre[wid] + *s_boff;
    #pragma unroll
    for (int j = 0; j < 4; ++j) {
        if (base + j < NE) { offsets[base + j] = run; cursor[base + j] = run; run += c[j]; }
    }
    if (base == 0 && b == 0) offsets[NE] = E;
}

__device__ inline void gather_node(int node, const int* offsets, const uint2* rdw,
                                   const unsigned* P1h, const unsigned* P2h,
                                   const unsigned* P3h, float* out, int lane) {
    const int lo = offsets[node], hi = offsets[node + 1];
    const unsigned p1 = P1h[(size_t)node * 64 + lane];   // hoisted
    float axp[4] = {0.f,0.f,0.f,0.f};
    float ayp[4] = {0.f,0.f,0.f,0.f};
    float wsp[4] = {0.f,0.f,0.f,0.f};
    for (int i = lo; i < hi; i += 4) {
        uint2 e[4];
        float wgt[4];
        #pragma unroll
        for (int j = 0; j < 4; ++j) {
            const int idx = min(i + j, hi - 1);
            e[j] = rdw[idx];
            wgt[j] = (i + j < hi) ? __uint_as_float(e[j].y) : 0.0f;
        }
        unsigned v2[4], v3[4];
        #pragma unroll
        for (int j = 0; j < 4; ++j) {
            v2[j] = P2h[(size_t)(e[j].x >> 17) * 64 + lane];
            v3[j] = P3h[(size_t)(e[j].x & 0x1FFFFu) * 64 + lane];
        }
        #pragma unroll
        for (int j = 0; j < 4; ++j) {
            axp[j] += wgt[j] * (unpack_lo(v2[j]) + unpack_lo(v3[j]));
            ayp[j] += wgt[j] * (unpack_hi(v2[j]) + unpack_hi(v3[j]));
            wsp[j] += wgt[j];
        }
    }
    const float ax = (axp[0] + axp[1]) + (axp[2] + axp[3]);
    const float ay = (ayp[0] + ayp[1]) + (ayp[2] + ayp[3]);
    const float inv = 1.0f / ((wsp[0] + wsp[1]) + (wsp[2] + wsp[3]));
    float v0 = unpack_lo(p1) + ax * inv;
    float v1 = unpack_hi(p1) + ay * inv;
    v0 = (v0 > 0.0f) ? v0 : (__expf(v0) - 1.0f);
    v1 = (v1 > 0.0f) ? v1 : (__expf(v1) - 1.0f);
    *(float2*)(out + (size_t)node * DIM + (lane << 1)) = make_float2(v0, v1);
}

// ---------------------------------------------------------------------------
// Cooperative stage 2 (grid sized to co-resident capacity at runtime)
// ---------------------------------------------------------------------------
__global__ __launch_bounds__(256) void stage2_kernel(
        const int* __restrict__ T,
        const float* __restrict__ q1, const float* __restrict__ q2,
        const float* __restrict__ q3, const float* __restrict__ b_a2,
        int* __restrict__ counts, int* __restrict__ bsum,
        int* __restrict__ offsets, int* __restrict__ cursor,
        uint2* __restrict__ rdw,
        const unsigned* __restrict__ P1h, const unsigned* __restrict__ P2h,
        const unsigned* __restrict__ P3h, float* __restrict__ out,
        int NE, int E, int NB) {
    cg::grid_group grid = cg::this_grid();
    const int b = blockIdx.x;
    const int t = threadIdx.x;
    __shared__ int ws[4];
    __shared__ int s_boff, wsum[4], wpre[4];

    if (b < NB) phaseA_bsum(counts, bsum, NE, b, t, ws);
    __threadfence();
    grid.sync();

    if (b < NB) phaseB_write(counts, bsum, offsets, cursor, NE, E, NB, b, t, &s_boff, wsum, wpre);
    __threadfence();
    grid.sync();

    const float qc = b_a2[0];
    for (int e = b * 256 + t; e < E; e += (int)gridDim.x * 256) {
        const int s = T[e], r = T[E + e], d = T[2 * E + e];
        float bb = q1[s] + q2[r] + q3[d] + qc;
        bb = (bb > 0.0f) ? bb : 0.01f * bb;
        const float wv = __expf(bb);
        const int pos = atomicAdd(&cursor[s], 1);
        rdw[pos] = make_uint2(((unsigned)r << 17) | (unsigned)d, __float_as_uint(wv));
    }
    __threadfence();
    grid.sync();

    const int lane = t & 63;
    const int wv = t >> 6;
    for (int nb = b; nb * 4 < NE; nb += (int)gridDim.x) {
        const int node = nb * 4 + wv;
        if (node < NE) gather_node(node, offsets, rdw, P1h, P2h, P3h, out, lane);
    }
}

// ---- fallback standalone kernels -------------------------------------------
__global__ __launch_bounds__(256) void scan_bsum_kernel(const int* __restrict__ counts,
                                                        int* __restrict__ bsum, int n) {
    __shared__ int ws[4];
    phaseA_bsum(counts, bsum, n, blockIdx.x, threadIdx.x, ws);
}

__global__ __launch_bounds__(256) void scan_write_kernel(const int* __restrict__ counts,
        const int* __restrict__ bsum, int* __restrict__ offsets, int* __restrict__ cursor,
        int n, int total, int nb) {
    __shared__ int s_boff, wsum[4], wpre[4];
    phaseB_write(counts, bsum, offsets, cursor, n, total, nb, blockIdx.x, threadIdx.x,
                 &s_boff, wsum, wpre);
}

__global__ void scatter_kernel(const int* __restrict__ T, const float* __restrict__ q1,
                               const float* __restrict__ q2, const float* __restrict__ q3,
                               const float* __restrict__ b_a2, int* __restrict__ cursor,
                               uint2* __restrict__ rdw, int E) {
    const int e = blockIdx.x * blockDim.x + threadIdx.x;
    if (e >= E) return;
    const int s = T[e], r = T[E + e], d = T[2 * E + e];
    float b = q1[s] + q2[r] + q3[d] + b_a2[0];
    b = (b > 0.0f) ? b : 0.01f * b;
    const float wv = __expf(b);
    const int pos = atomicAdd(&cursor[s], 1);
    rdw[pos] = make_uint2(((unsigned)r << 17) | (unsigned)d, __float_as_uint(wv));
}

__global__ void gather_kernel(const int* __restrict__ offsets, const uint2* __restrict__ rdw,
                              const unsigned* __restrict__ P1h, const unsigned* __restrict__ P2h,
                              const unsigned* __restrict__ P3h, float* __restrict__ out, int n) {
    const int node = (blockIdx.x << 2) + (threadIdx.x >> 6);
    if (node >= n) return;
    gather_node(node, offsets, rdw, P1h, P2h, P3h, out, threadIdx.x & 63);
}

extern "C" void kernel_launch(void* const* d_in, const int* in_sizes, int n_in,
                              void* d_out, int out_size, void* d_ws, size_t ws_size,
                              hipStream_t stream) {
    const int*   T    = (const int*)d_in[0];
    const float* ent  = (const float*)d_in[1];
    const float* rel  = (const float*)d_in[2];
    const float* W_a  = (const float*)d_in[4];
    const float* b_a  = (const float*)d_in[5];
    const float* W_a2 = (const float*)d_in[6];
    const float* b_a2 = (const float*)d_in[7];
    float* out = (float*)d_out;

    const int E  = in_sizes[0] / 3;
    const int NE = in_sizes[1] / DIM;
    const int NR = in_sizes[2] / DIM;
    const int NB = (NE + 1023) / 1024;         // scan chunks (<=64)
    const int GB = (NE + 127) / 128;           // GEMM blocks (both halves each)
    const int HB = 128;                        // hist blocks (512 thr)
    const int RB = (NR + 15) / 16;             // rel-proj blocks (512 thr)

    float* ws = (float*)d_ws;
    size_t off = 0;
    unsigned* P1h = (unsigned*)(ws + off); off += (size_t)NE * 64;
    unsigned* P3h = (unsigned*)(ws + off); off += (size_t)NE * 64;
    unsigned* P2h = (unsigned*)(ws + off); off += (size_t)NR * 64;
    unsigned short* Wt = (unsigned short*)(ws + off); off += 256 * DIM / 2;
    float* q1   = ws + off; off += NE;
    float* q3   = ws + off; off += NE;
    float* q2   = ws + off; off += NR + 64;
    int* counts  = (int*)(ws + off); off += NE;
    int* offsets = (int*)(ws + off); off += NE + 64;
    int* cursor  = (int*)(ws + off); off += NE;
    int* bsum    = (int*)(ws + off); off += 64;
    uint2* rdw   = (uint2*)(ws + off); off += (size_t)E * 2;

    // W transpose+bf16 pack; also zero counts
    wprep_kernel<<<256, 128, 0, stream>>>(W_a, Wt, counts, NE);

    // fused stage 1: ent GEMM (both halves) + hist + rel projection
    stage1_kernel<<<GB + HB + RB, 512, 0, stream>>>(
        ent, rel, T, Wt, W_a + 128 * DIM, b_a, W_a2,
        P1h, P3h, P2h, q1, q3, q2, counts, NE, NR, E, GB, HB, RB);

    // cooperative stage 2, grid sized to measured co-resident capacity
    int dev = 0;
    hipGetDevice(&dev);
    int numCU = 0;
    hipDeviceGetAttribute(&numCU, hipDeviceAttributeMultiprocessorCount, dev);
    int blocksPerCU = 0;
    hipError_t qerr = hipOccupancyMaxActiveBlocksPerMultiprocessor(
        &blocksPerCU, (const void*)stage2_kernel, 256, 0);

    bool coop_ok = false;
    if (qerr == hipSuccess && blocksPerCU > 0 && numCU > 0) {
        int grid = blocksPerCU * numCU;
        if (grid >= NB) {
            void* args[] = {
                (void*)&T, (void*)&q1, (void*)&q2, (void*)&q3, (void*)&b_a2,
                (void*)&counts, (void*)&bsum, (void*)&offsets, (void*)&cursor,
                (void*)&rdw, (void*)&P1h, (void*)&P2h, (void*)&P3h, (void*)&out,
                (void*)&NE, (void*)&E, (void*)&NB
            };
            hipError_t lerr = hipLaunchCooperativeKernel((void*)stage2_kernel,
                                                         dim3(grid), dim3(256),
                                                         args, 0, stream);
            coop_ok = (lerr == hipSuccess);
        }
    }

    if (!coop_ok) {
        // fallback: proven 4-dispatch chain
        scan_bsum_kernel<<<NB, 256, 0, stream>>>(counts, bsum, NE);
        scan_write_kernel<<<NB, 256, 0, stream>>>(counts, bsum, offsets, cursor, NE, E, NB);
        scatter_kernel<<<(E + 255) / 256, 256, 0, stream>>>(T, q1, q2, q3, b_a2, cursor, rdw, E);
        gather_kernel<<<(NE + 3) / 4, 256, 0, stream>>>(offsets, rdw, P1h, P2h, P3h, out, NE);
    }
}

// Round 14
// 98.480 us; speedup vs baseline: 8.0742x; 8.0742x over previous
//
#include <hip/hip_runtime.h>

#define DIM 128

typedef __attribute__((ext_vector_type(8))) short bf16x8;
typedef __attribute__((ext_vector_type(4))) float f32x4;

// ---- bf16 helpers (RNE) ----------------------------------------------------
__device__ inline unsigned short to_bf16(float f) {
    unsigned u = __float_as_uint(f);
    u = (u + 0x7FFFu + ((u >> 16) & 1u)) >> 16;
    return (unsigned short)u;
}
__device__ inline unsigned pack_bf16(float lo, float hi) {
    return (unsigned)to_bf16(lo) | ((unsigned)to_bf16(hi) << 16);
}
__device__ inline float unpack_lo(unsigned v) { return __uint_as_float(v << 16); }
__device__ inline float unpack_hi(unsigned v) { return __uint_as_float(v & 0xFFFF0000u); }

// ---------------------------------------------------------------------------
__global__ void wprep_kernel(const float* __restrict__ W_a, unsigned short* __restrict__ Wt,
                             int* __restrict__ counts, int n) {
    const int c = blockIdx.x;          // 0..255
    const int k = threadIdx.x;         // 0..127
    const int srow = (c < 128) ? k : (256 + k);
    const int scol = (c < 128) ? c : (c - 128);
    Wt[c * DIM + k] = to_bf16(W_a[srow * DIM + scol]);
    for (int i = blockIdx.x * 128 + k; i < n; i += 256 * 128) counts[i] = 0;
}

// ---------------------------------------------------------------------------
// Fused stage 1 (512 threads/block): GEMM (both halves) | hist | rel-proj
// (R11-proven)
// ---------------------------------------------------------------------------
__global__ __launch_bounds__(512, 4) void stage1_kernel(
        const float* __restrict__ ent, const float* __restrict__ rel,
        const int* __restrict__ T, const unsigned short* __restrict__ Wt,
        const float* __restrict__ W_rel, const float* __restrict__ b_a,
        const float* __restrict__ Wa2,
        unsigned* __restrict__ P1h, unsigned* __restrict__ P3h, unsigned* __restrict__ P2h,
        float* __restrict__ q1, float* __restrict__ q3, float* __restrict__ q2,
        int* __restrict__ counts, int NE, int NR, int E, int GB, int HB, int RB) {
    __shared__ unsigned smem[16640];   // 66.6 KB: B [256][64]dw swz / out [256][65]dw
    int b = blockIdx.x;
    const int t = threadIdx.x;

    if (b < GB) {
        const int mrow = b * 128;
        const int wv = t >> 6;
        const int lane = t & 63;
        const int g = lane >> 4, m = lane & 15;

        #pragma unroll
        for (int i = 0; i < 8; ++i) {
            const int ci  = i * 8 + wv;
            const int row = ci * 4 + (lane >> 4);
            const int dw0 = (lane & 15) * 4;
            const int sdw = dw0 ^ ((row & 7) << 2);
            const uint4 v = *(const uint4*)(Wt + row * DIM + sdw * 2);
            *(uint4*)&smem[ci * 256 + lane * 4] = v;
        }

        const int rowA = min(mrow + wv * 16 + m, NE - 1);
        const float* arow = ent + (size_t)rowA * DIM;
        bf16x8 afrag[4];
        #pragma unroll
        for (int kk = 0; kk < 4; ++kk) {
            const float4 u0 = *(const float4*)(arow + kk * 32 + g * 8);
            const float4 u1 = *(const float4*)(arow + kk * 32 + g * 8 + 4);
            bf16x8 a;
            a[0] = (short)to_bf16(u0.x); a[1] = (short)to_bf16(u0.y);
            a[2] = (short)to_bf16(u0.z); a[3] = (short)to_bf16(u0.w);
            a[4] = (short)to_bf16(u1.x); a[5] = (short)to_bf16(u1.y);
            a[6] = (short)to_bf16(u1.z); a[7] = (short)to_bf16(u1.w);
            afrag[kk] = a;
        }
        __syncthreads();

        f32x4 acc[2][8];
        #pragma unroll
        for (int h = 0; h < 2; ++h)
            #pragma unroll
            for (int ct = 0; ct < 8; ++ct) acc[h][ct] = (f32x4){0.f, 0.f, 0.f, 0.f};
        #pragma unroll
        for (int kk = 0; kk < 4; ++kk) {
            #pragma unroll
            for (int h = 0; h < 2; ++h) {
                #pragma unroll
                for (int ct = 0; ct < 8; ++ct) {
                    const int brow = h * 128 + ct * 16 + m;
                    const int dw = (kk * 16 + g * 4) ^ ((brow & 7) << 2);
                    const bf16x8 bb = *(const bf16x8*)&smem[brow * 64 + dw];
                    acc[h][ct] = __builtin_amdgcn_mfma_f32_16x16x32_bf16(afrag[kk], bb, acc[h][ct], 0, 0, 0);
                }
            }
        }
        __syncthreads();

        unsigned short* lds16 = (unsigned short*)smem;   // [256][130] ushort
        #pragma unroll
        for (int h = 0; h < 2; ++h) {
            float* __restrict__ qo = h ? q3 : q1;
            float qp[4] = {0.f, 0.f, 0.f, 0.f};
            #pragma unroll
            for (int ct = 0; ct < 8; ++ct) {
                const int c = ct * 16 + m;
                const float bias = h ? 0.0f : b_a[c];
                const float wa2  = Wa2[c];
                #pragma unroll
                for (int r = 0; r < 4; ++r) {
                    const float v = acc[h][ct][r] + bias;
                    qp[r] += v * wa2;
                    lds16[(h * 128 + wv * 16 + g * 4 + r) * 130 + c] = to_bf16(v);
                }
            }
            #pragma unroll
            for (int r = 0; r < 4; ++r) {
                float v = qp[r];
                #pragma unroll
                for (int o = 1; o < 16; o <<= 1) v += __shfl_xor(v, o);
                const int row = mrow + wv * 16 + g * 4 + r;
                if (m == 0 && row < NE) qo[row] = v;
            }
        }
        __syncthreads();
        #pragma unroll 4
        for (int i = 0; i < 32; ++i) {
            const int linear = i * 512 + t;
            const int row = linear >> 6, d = linear & 63;
            const int rg = mrow + (row & 127);
            unsigned* __restrict__ Ph = (row < 128) ? P1h : P3h;
            if (rg < NE) Ph[(size_t)rg * 64 + d] = smem[row * 65 + d];
        }
        return;
    }
    b -= GB;

    if (b < HB) {
        for (int e = b * 512 + t; e < E; e += HB * 512)
            atomicAdd(&counts[T[e]], 1);
        return;
    }
    b -= HB;

    {
        float* xs   = (float*)smem;
        float* sred = (float*)(smem + 2048);
        const int row0 = b * 16;
        const int qr = t >> 7;
        const int tc = t & 127;
        #pragma unroll
        for (int e = 0; e < 4; ++e) {
            int row = row0 + qr * 4 + e;
            xs[(qr * 4 + e) * DIM + tc] = (row < NR) ? rel[(size_t)row * DIM + tc] : 0.0f;
        }
        __syncthreads();
        float acc[4] = {0.f, 0.f, 0.f, 0.f};
        #pragma unroll 4
        for (int k = 0; k < DIM; ++k) {
            const float wv = W_rel[k * DIM + tc];
            #pragma unroll
            for (int e = 0; e < 4; ++e) acc[e] += xs[(qr * 4 + e) * DIM + k] * wv;
        }
        const float wa2 = Wa2[tc];
        const int lane = t & 63;
        #pragma unroll
        for (int e = 0; e < 4; ++e) {
            float v = acc[e] * wa2;
            #pragma unroll
            for (int o = 32; o > 0; o >>= 1) v += __shfl_down(v, o);
            if (lane == 0) sred[(qr * 4 + e) * 2 + ((t >> 6) & 1)] = v;
        }
        __syncthreads();
        #pragma unroll
        for (int e = 0; e < 4; ++e) {
            int row = row0 + qr * 4 + e;
            float hi = __shfl_down(acc[e], 1);
            if (row < NR && (tc & 1) == 0)
                P2h[(size_t)row * 64 + (tc >> 1)] = pack_bf16(acc[e], hi);
        }
        if (t < 16) {
            int row = row0 + t;
            if (row < NR) q2[row] = sred[t * 2] + sred[t * 2 + 1];
        }
    }
}

// ---------------------------------------------------------------------------
__device__ inline int wave_incl_scan(int v) {
    const int lane = threadIdx.x & 63;
    #pragma unroll
    for (int o = 1; o < 64; o <<= 1) {
        int u = __shfl_up(v, o);
        if (lane >= o) v += u;
    }
    return v;
}

__global__ __launch_bounds__(256) void scan_bsum_kernel(const int* __restrict__ counts,
                                                        int* __restrict__ bsum, int n) {
    __shared__ int ws[4];
    const int t = threadIdx.x;
    const int base = blockIdx.x * 1024 + t * 4;
    int s = 0;
    #pragma unroll
    for (int j = 0; j < 4; ++j) if (base + j < n) s += counts[base + j];
    #pragma unroll
    for (int o = 32; o > 0; o >>= 1) s += __shfl_down(s, o);
    if ((t & 63) == 0) ws[t >> 6] = s;
    __syncthreads();
    if (t == 0) bsum[blockIdx.x] = ws[0] + ws[1] + ws[2] + ws[3];
}

__global__ __launch_bounds__(256) void scan_write_kernel(const int* __restrict__ counts,
        const int* __restrict__ bsum, int* __restrict__ offsets, int* __restrict__ cursor,
        int n, int total, int nb) {
    __shared__ int s_boff, wsum[4], wpre[4];
    const int t = threadIdx.x;
    if (t < 64) {
        int v = (t < nb) ? bsum[t] : 0;
        int incl = wave_incl_scan(v);
        int ex = incl - v;
        int want = __shfl(ex, (int)blockIdx.x);
        if (t == 0) s_boff = want;
    }
    const int base = blockIdx.x * 1024 + t * 4;
    int c[4];
    int s = 0;
    #pragma unroll
    for (int j = 0; j < 4; ++j) {
        c[j] = (base + j < n) ? counts[base + j] : 0;
        s += c[j];
    }
    int incl = wave_incl_scan(s);
    const int wid = t >> 6, lane = t & 63;
    if (lane == 63) wsum[wid] = incl;
    __syncthreads();
    if (t == 0) {
        int run = 0;
        #pragma unroll
        for (int k = 0; k < 4; ++k) { wpre[k] = run; run += wsum[k]; }
    }
    __syncthreads();
    int run = incl - s + wpre[wid] + s_boff;
    #pragma unroll
    for (int j = 0; j < 4; ++j) {
        if (base + j < n) { offsets[base + j] = run; cursor[base + j] = run; run += c[j]; }
    }
    if (base == 0 && blockIdx.x == 0) offsets[n] = total;
}

// ---------------------------------------------------------------------------
__global__ void scatter_kernel(const int* __restrict__ T, const float* __restrict__ q1,
                               const float* __restrict__ q2, const float* __restrict__ q3,
                               const float* __restrict__ b_a2, int* __restrict__ cursor,
                               uint2* __restrict__ rdw, int E) {
    const int e = blockIdx.x * blockDim.x + threadIdx.x;
    if (e >= E) return;
    const int s = T[e], r = T[E + e], d = T[2 * E + e];
    float b = q1[s] + q2[r] + q3[d] + b_a2[0];
    b = (b > 0.0f) ? b : 0.01f * b;
    const float wv = __expf(b);
    const int pos = atomicAdd(&cursor[s], 1);
    rdw[pos] = make_uint2(((unsigned)r << 17) | (unsigned)d, __float_as_uint(wv));
}

// ---------------------------------------------------------------------------
// one wave per node, predicated unroll x8 (16 row-loads in flight):
// gather bf16 rows, normalize, add P1b, elu. Write-only out.
// ---------------------------------------------------------------------------
__global__ void gather_kernel(const int* __restrict__ offsets, const uint2* __restrict__ rdw,
                              const unsigned* __restrict__ P1h, const unsigned* __restrict__ P2h,
                              const unsigned* __restrict__ P3h, float* __restrict__ out, int n) {
    const int node = (blockIdx.x << 2) + (threadIdx.x >> 6);   // 4 waves/block
    if (node >= n) return;
    const int lane = threadIdx.x & 63;
    const int lo = offsets[node], hi = offsets[node + 1];
    const unsigned p1 = P1h[(size_t)node * 64 + lane];         // hoisted
    float axp[4] = {0.f,0.f,0.f,0.f};
    float ayp[4] = {0.f,0.f,0.f,0.f};
    float wsp[4] = {0.f,0.f,0.f,0.f};
    for (int i = lo; i < hi; i += 8) {
        uint2 e[8];
        float wgt[8];
        #pragma unroll
        for (int j = 0; j < 8; ++j) {
            const int idx = min(i + j, hi - 1);
            e[j] = rdw[idx];
            wgt[j] = (i + j < hi) ? __uint_as_float(e[j].y) : 0.0f;
        }
        unsigned v2[8], v3[8];
        #pragma unroll
        for (int j = 0; j < 8; ++j) {
            v2[j] = P2h[(size_t)(e[j].x >> 17) * 64 + lane];
            v3[j] = P3h[(size_t)(e[j].x & 0x1FFFFu) * 64 + lane];
        }
        #pragma unroll
        for (int j = 0; j < 8; ++j) {
            axp[j & 3] += wgt[j] * (unpack_lo(v2[j]) + unpack_lo(v3[j]));
            ayp[j & 3] += wgt[j] * (unpack_hi(v2[j]) + unpack_hi(v3[j]));
            wsp[j & 3] += wgt[j];
        }
    }
    const float ax = (axp[0] + axp[1]) + (axp[2] + axp[3]);
    const float ay = (ayp[0] + ayp[1]) + (ayp[2] + ayp[3]);
    const float inv = 1.0f / ((wsp[0] + wsp[1]) + (wsp[2] + wsp[3]));
    float v0 = unpack_lo(p1) + ax * inv;
    float v1 = unpack_hi(p1) + ay * inv;
    v0 = (v0 > 0.0f) ? v0 : (__expf(v0) - 1.0f);
    v1 = (v1 > 0.0f) ? v1 : (__expf(v1) - 1.0f);
    *(float2*)(out + (size_t)node * DIM + (lane << 1)) = make_float2(v0, v1);
}

extern "C" void kernel_launch(void* const* d_in, const int* in_sizes, int n_in,
                              void* d_out, int out_size, void* d_ws, size_t ws_size,
                              hipStream_t stream) {
    const int*   T    = (const int*)d_in[0];
    const float* ent  = (const float*)d_in[1];
    const float* rel  = (const float*)d_in[2];
    const float* W_a  = (const float*)d_in[4];
    const float* b_a  = (const float*)d_in[5];
    const float* W_a2 = (const float*)d_in[6];
    const float* b_a2 = (const float*)d_in[7];
    float* out = (float*)d_out;

    const int E  = in_sizes[0] / 3;
    const int NE = in_sizes[1] / DIM;
    const int NR = in_sizes[2] / DIM;
    const int NB = (NE + 1023) / 1024;         // scan chunks (<=64)
    const int GB = (NE + 127) / 128;           // GEMM blocks (both halves each)
    const int HB = 128;                        // hist blocks (512 thr)
    const int RB = (NR + 15) / 16;             // rel-proj blocks (512 thr)

    float* ws = (float*)d_ws;
    size_t off = 0;
    unsigned* P1h = (unsigned*)(ws + off); off += (size_t)NE * 64;
    unsigned* P3h = (unsigned*)(ws + off); off += (size_t)NE * 64;
    unsigned* P2h = (unsigned*)(ws + off); off += (size_t)NR * 64;
    unsigned short* Wt = (unsigned short*)(ws + off); off += 256 * DIM / 2;
    float* q1   = ws + off; off += NE;
    float* q3   = ws + off; off += NE;
    float* q2   = ws + off; off += NR + 64;
    int* counts  = (int*)(ws + off); off += NE;
    int* offsets = (int*)(ws + off); off += NE + 64;
    int* cursor  = (int*)(ws + off); off += NE;
    int* bsum    = (int*)(ws + off); off += 64;
    uint2* rdw   = (uint2*)(ws + off); off += (size_t)E * 2;

    // W transpose+bf16 pack; also zero counts
    wprep_kernel<<<256, 128, 0, stream>>>(W_a, Wt, counts, NE);

    // fused stage 1: ent GEMM (both halves) + hist + rel projection
    stage1_kernel<<<GB + HB + RB, 512, 0, stream>>>(
        ent, rel, T, Wt, W_a + 128 * DIM, b_a, W_a2,
        P1h, P3h, P2h, q1, q3, q2, counts, NE, NR, E, GB, HB, RB);

    // CSR scan
    scan_bsum_kernel<<<NB, 256, 0, stream>>>(counts, bsum, NE);
    scan_write_kernel<<<NB, 256, 0, stream>>>(counts, bsum, offsets, cursor, NE, E, NB);

    // fused weight + scatter (8 B payload per edge)
    scatter_kernel<<<(E + 255) / 256, 256, 0, stream>>>(T, q1, q2, q3, b_a2, cursor, rdw, E);

    // gather + normalize + elu (predicated unroll x8)
    gather_kernel<<<(NE + 3) / 4, 256, 0, stream>>>(offsets, rdw, P1h, P2h, P3h, out, NE);
}